// Round 15
// baseline (705.356 us; speedup 1.0000x reference)
//
#include <hip/hip_runtime.h>
#include <math.h>

#define B_GRAPHS 16384
#define N_NODES  524288
#define E_EDGES  1048576
#define D_EMB    128
#define D_STATE  64
#define HID      32
#define PADK     136       // bf16 elems/row -> 272B row stride (16B aligned)
#define WPB      4         // waves per block; each wave owns one 32-node window
#define NWIN     (N_NODES / 32)
#define WIN_BLOCKS (NWIN / WPB)           // 4096
#define NB_FIN     (B_GRAPHS * 32 / 256)  // 2048
#define NB_COPY    (E_EDGES * 2 / 256)    // 8192  (2 threads/edge, 4 f32x4 each)
#define NB_STATE   (E_EDGES * 4 / 256)    // 16384 (4 threads/edge, 4 f32x4 each)

typedef __attribute__((ext_vector_type(8))) short short8;
typedef __attribute__((ext_vector_type(4))) float f32x4;

__device__ __forceinline__ unsigned short f2bf(float f) {
    unsigned int u = __builtin_bit_cast(unsigned int, f);
    u += 0x7fffu + ((u >> 16) & 1u);
    return (unsigned short)(u >> 16);
}
__device__ __forceinline__ float bf2f(unsigned short s) {
    unsigned int u = ((unsigned int)s) << 16;
    return __builtin_bit_cast(float, u);
}

// ---------- K1: prep = hb (blocks 0..2047) + zero accum/Sbuf (blocks 2048..4095) ----------
__global__ __launch_bounds__(256) void prep_kernel(
    const float* __restrict__ state_emb, const float* __restrict__ W1,
    const float* __restrict__ b1, const int* __restrict__ state,
    float* __restrict__ hb, f32x4* __restrict__ out_x4, f32x4* __restrict__ Sbuf4)
{
    const int bid = blockIdx.x, t = threadIdx.x;
    if (bid < 2048) {                       // hb part
        int j = t & 31;
        int g = bid * 8 + (t >> 5);
        int st = state[g];
        const float* zs = state_emb + st * D_STATE;
        float acc = b1[j];
        #pragma unroll 8
        for (int k = 0; k < D_STATE; ++k)
            acc += zs[k] * W1[(D_EMB + k) * HID + j];
        hb[g * HID + j] = acc;
    } else {                                // zero accumulator half + Sbuf
        int i = (bid - 2048) * 256 + t;     // 0 .. B*32-1
        int g = i >> 5, q = i & 31;
        f32x4 z = {0.f, 0.f, 0.f, 0.f};
        out_x4[(size_t)g * 64 + 32 + q] = z;
        if (i < B_GRAPHS / 4) Sbuf4[i] = z;
    }
}

// ---------- K2: window kernel (standalone; W1 frags in regs; boundary atomics) ----------
__global__ __launch_bounds__(256, 4) void window_kernel(
    const float* __restrict__ z_atom,
    const float* __restrict__ W1,
    const float* __restrict__ W2,
    const float* __restrict__ b2,
    const int*   __restrict__ batch,
    const float* __restrict__ hb,
    float*       __restrict__ out_x,
    float*       __restrict__ Sbuf)
{
    __shared__ unsigned short s_zb[WPB][32][PADK];

    const int t    = threadIdx.x;
    const int lane = t & 63;
    const int w    = t >> 6;
    const int l15  = lane & 15;
    const int kc   = lane >> 4;        // 0..3

    // W1^T fragments in registers
    short8 wa[2][4];
    #pragma unroll
    for (int jh = 0; jh < 2; ++jh)
        #pragma unroll
        for (int kb = 0; kb < 4; ++kb)
            #pragma unroll
            for (int i = 0; i < 8; ++i) {
                int k = kb * 32 + kc * 8 + i;
                wa[jh][kb][i] = (short)f2bf(W1[k * HID + jh * 16 + l15]);
            }

    const float b2v = b2[0];
    float w2v[2][4];
    #pragma unroll
    for (int jh = 0; jh < 2; ++jh)
        #pragma unroll
        for (int r = 0; r < 4; ++r)
            w2v[jh][r] = W2[16 * jh + 4 * kc + r];

    unsigned short (*zb)[PADK] = s_zb[w];

    const int win = blockIdx.x * WPB + w;
    const int c0  = win * 32;
    int bv = 0;
    if (lane < 32) bv = batch[c0 + lane];

    const int leftN  = (c0 > 0) ? batch[c0 - 1] : -2;
    const int rightN = (c0 + 32 < N_NODES) ? batch[c0 + 32] : -2;

    float4 hbf[2][2];
    #pragma unroll
    for (int nh = 0; nh < 2; ++nh) {
        int bn = __shfl(bv, l15 + 16 * nh);
        hbf[nh][0] = *(const float4*)&hb[(size_t)bn * HID + 4 * kc];
        hbf[nh][1] = *(const float4*)&hb[(size_t)bn * HID + 16 + 4 * kc];
    }

    const f32x4* za4 = (const f32x4*)z_atom + (size_t)c0 * (D_EMB / 4);
    #pragma unroll
    for (int half = 0; half < 2; ++half) {
        f32x4 tmp[8];
        #pragma unroll
        for (int it = 0; it < 8; ++it) {
            int idx = (half * 8 + it) * 64 + lane;
            int n = idx >> 5, c = idx & 31;
            tmp[it] = __builtin_nontemporal_load(&za4[n * (D_EMB / 4) + c]);
        }
        #pragma unroll
        for (int it = 0; it < 8; ++it) {
            int idx = (half * 8 + it) * 64 + lane;
            int n = idx >> 5, c = idx & 31;
            f32x4 v = tmp[it];
            unsigned lo = (unsigned)f2bf(v[0]) | ((unsigned)f2bf(v[1]) << 16);
            unsigned hi = (unsigned)f2bf(v[2]) | ((unsigned)f2bf(v[3]) << 16);
            *(uint2*)&zb[n][c * 4] = make_uint2(lo, hi);
        }
    }

    f32x4 acc[2][2] = {{{0.f,0.f,0.f,0.f},{0.f,0.f,0.f,0.f}},
                       {{0.f,0.f,0.f,0.f},{0.f,0.f,0.f,0.f}}};
    #pragma unroll
    for (int kb = 0; kb < 4; ++kb) {
        short8 q0 = *(const short8*)&zb[l15][kb * 32 + kc * 8];
        short8 q1 = *(const short8*)&zb[16 + l15][kb * 32 + kc * 8];
        acc[0][0] = __builtin_amdgcn_mfma_f32_16x16x32_bf16(wa[0][kb], q0, acc[0][0], 0, 0, 0);
        acc[1][0] = __builtin_amdgcn_mfma_f32_16x16x32_bf16(wa[1][kb], q0, acc[1][0], 0, 0, 0);
        acc[0][1] = __builtin_amdgcn_mfma_f32_16x16x32_bf16(wa[0][kb], q1, acc[0][1], 0, 0, 0);
        acc[1][1] = __builtin_amdgcn_mfma_f32_16x16x32_bf16(wa[1][kb], q1, acc[1][1], 0, 0, 0);
    }

    float pt[2];
    #pragma unroll
    for (int nh = 0; nh < 2; ++nh) {
        float part = 0.f;
        #pragma unroll
        for (int r = 0; r < 4; ++r) {
            float h = acc[0][nh][r] + (&hbf[nh][0].x)[r];
            h = h > 0.f ? h : 0.01f * h;
            part += h * w2v[0][r];
        }
        #pragma unroll
        for (int r = 0; r < 4; ++r) {
            float h = acc[1][nh][r] + (&hbf[nh][1].x)[r];
            h = h > 0.f ? h : 0.01f * h;
            part += h * w2v[1][r];
        }
        part += __shfl_xor(part, 16);
        part += __shfl_xor(part, 32);
        pt[nh] = __expf(part + b2v);
    }

    // pooling walk; interior graphs -> plain store; boundary graphs -> atomicAdd
    float u0 = 0.f, u1 = 0.f, ss = 0.f;
    int cur = __shfl(bv, 0);
    int a = 0;

    #pragma unroll 4
    for (int n = 0; n < 32; ++n) {
        int bn = __shfl(bv, n);
        if (bn != cur) {
            if (a == 0 && leftN == cur) {
                atomicAdd(&out_x[(size_t)cur * 256 + 128 + lane * 2], u0);
                atomicAdd(&out_x[(size_t)cur * 256 + 129 + lane * 2], u1);
                if (lane == 0) atomicAdd(&Sbuf[cur], ss);
            } else {
                *(float2*)&out_x[(size_t)cur * 256 + 128 + lane * 2] = make_float2(u0, u1);
                if (lane == 0) Sbuf[cur] = ss;
            }
            u0 = u1 = ss = 0.f;
            cur = bn; a = n;
        }
        float pn = (n < 16) ? __shfl(pt[0], n) : __shfl(pt[1], n - 16);
        unsigned zz = *(const unsigned*)&zb[n][lane * 2];
        u0 += pn * bf2f((unsigned short)(zz & 0xffffu));
        u1 += pn * bf2f((unsigned short)(zz >> 16));
        ss += pn;
    }
    {
        bool lb = (a == 0) && (leftN == cur);
        bool rb = (rightN == cur);
        if (lb || rb) {
            atomicAdd(&out_x[(size_t)cur * 256 + 128 + lane * 2], u0);
            atomicAdd(&out_x[(size_t)cur * 256 + 129 + lane * 2], u1);
            if (lane == 0) atomicAdd(&Sbuf[cur], ss);
        } else {
            *(float2*)&out_x[(size_t)cur * 256 + 128 + lane * 2] = make_float2(u0, u1);
            if (lane == 0) Sbuf[cur] = ss;
        }
    }
}

// ---------- K3: tail = finalize + edge copy (4x/thread) + edge state (4x/thread) ----------
__global__ __launch_bounds__(256) void tail_kernel(
    const float* __restrict__ z_mol,
    const float* __restrict__ Sbuf,
    float*       __restrict__ out_x,
    const f32x4* __restrict__ edge_attr4,
    const f32x4* __restrict__ state_emb4,
    const int*   __restrict__ state,
    const int*   __restrict__ eidx,
    const int*   __restrict__ batch,
    f32x4*       __restrict__ out_e4)
{
    const int bid = blockIdx.x, t = threadIdx.x;
    if (bid < NB_COPY) {
        // copy: 2 threads/edge, each moves 4 consecutive f32x4 (64B)
        int tid = bid * 256 + t;                  // e*2 + h
        int e = tid >> 1, h = tid & 1;
        #pragma unroll
        for (int i = 0; i < 4; ++i) {
            f32x4 v = __builtin_nontemporal_load(&edge_attr4[(size_t)tid * 4 + i]);
            __builtin_nontemporal_store(v, &out_e4[(size_t)e * 24 + h * 4 + i]);
        }
    } else if (bid < NB_COPY + NB_STATE) {
        // state: 4 threads/edge, each writes 4 consecutive f32x4 (64B)
        int tid = (bid - NB_COPY) * 256 + t;      // e*4 + qg
        int e = tid >> 2, qg = tid & 3;
        int n = eidx[e];
        int b = batch[n];
        int s = state[b];
        #pragma unroll
        for (int i = 0; i < 4; ++i) {
            f32x4 v = state_emb4[s * 16 + qg * 4 + i];
            __builtin_nontemporal_store(v, &out_e4[(size_t)e * 24 + 8 + qg * 4 + i]);
        }
    } else {
        // finalize: divide accum by S, copy z_mol
        int i = (bid - NB_COPY - NB_STATE) * 256 + t;   // B*32 threads
        int g = i >> 5, q = i & 31;
        f32x4 zm = *(const f32x4*)&z_mol[(size_t)g * D_EMB + q * 4];
        *(f32x4*)&out_x[(size_t)g * 256 + q * 4] = zm;
        float inv = 1.f / (Sbuf[g] + 1e-16f);
        f32x4 u = *(f32x4*)&out_x[(size_t)g * 256 + 128 + q * 4];
        u *= inv;
        *(f32x4*)&out_x[(size_t)g * 256 + 128 + q * 4] = u;
    }
}

extern "C" void kernel_launch(void* const* d_in, const int* in_sizes, int n_in,
                              void* d_out, int out_size, void* d_ws, size_t ws_size,
                              hipStream_t stream)
{
    const float* edge_attr = (const float*)d_in[0];
    const float* z_mol     = (const float*)d_in[1];
    const float* z_atom    = (const float*)d_in[2];
    const float* state_emb = (const float*)d_in[3];
    const float* W1        = (const float*)d_in[4];
    const float* b1        = (const float*)d_in[5];
    const float* W2        = (const float*)d_in[6];
    const float* b2        = (const float*)d_in[7];
    const int*   state     = (const int*)d_in[8];
    const int*   eidx      = (const int*)d_in[9];
    const int*   batch     = (const int*)d_in[10];

    float* out_x = (float*)d_out;
    float* out_e = out_x + (size_t)B_GRAPHS * 256;

    float* hbuf = (float*)d_ws;                                        // B*32 f32
    float* Sbuf = (float*)((char*)d_ws + (size_t)B_GRAPHS * HID * 4);  // B f32

    prep_kernel<<<4096, 256, 0, stream>>>(
        state_emb, W1, b1, state, hbuf, (f32x4*)out_x, (f32x4*)Sbuf);

    window_kernel<<<WIN_BLOCKS, 256, 0, stream>>>(
        z_atom, W1, W2, b2, batch, hbuf, out_x, Sbuf);

    tail_kernel<<<NB_COPY + NB_STATE + NB_FIN, 256, 0, stream>>>(
        z_mol, Sbuf, out_x,
        (const f32x4*)edge_attr, (const f32x4*)state_emb,
        state, eidx, batch, (f32x4*)out_e);
}

// Round 16
// 167.763 us; speedup vs baseline: 4.2045x; 4.2045x over previous
//
#include <hip/hip_runtime.h>
#include <math.h>

#define B_GRAPHS 16384
#define N_NODES  524288
#define E_EDGES  1048576
#define D_EMB    128
#define D_STATE  64
#define HID      32
#define PADK     136       // bf16 elems/row -> 272B row stride (16B aligned)
#define WPB      4         // waves per block; each wave owns one 32-node window
#define NWIN     (N_NODES / 32)
#define WIN_BLOCKS (NWIN / WPB)          // 4096
#define NB_FIN     (B_GRAPHS * 32 / 256) // 2048
#define NB_COPY    (E_EDGES * 8 / 256)   // 32768
#define NB_STATE   (E_EDGES * 16 / 256)  // 65536

typedef __attribute__((ext_vector_type(8))) short short8;
typedef __attribute__((ext_vector_type(4))) float f32x4;

__device__ __forceinline__ unsigned short f2bf(float f) {
    unsigned int u = __builtin_bit_cast(unsigned int, f);
    u += 0x7fffu + ((u >> 16) & 1u);
    return (unsigned short)(u >> 16);
}
__device__ __forceinline__ float bf2f(unsigned short s) {
    unsigned int u = ((unsigned int)s) << 16;
    return __builtin_bit_cast(float, u);
}

// ---------- K1: prep = hb (blocks 0..2047) + zero accum/Sbuf (blocks 2048..4095) ----------
__global__ __launch_bounds__(256) void prep_kernel(
    const float* __restrict__ state_emb, const float* __restrict__ W1,
    const float* __restrict__ b1, const int* __restrict__ state,
    float* __restrict__ hb, f32x4* __restrict__ out_x4, f32x4* __restrict__ Sbuf4)
{
    const int bid = blockIdx.x, t = threadIdx.x;
    if (bid < 2048) {                       // hb part
        int j = t & 31;
        int g = bid * 8 + (t >> 5);
        int st = state[g];
        const float* zs = state_emb + st * D_STATE;
        float acc = b1[j];
        #pragma unroll 8
        for (int k = 0; k < D_STATE; ++k)
            acc += zs[k] * W1[(D_EMB + k) * HID + j];
        hb[g * HID + j] = acc;
    } else {                                // zero accumulator half + Sbuf
        int i = (bid - 2048) * 256 + t;     // 0 .. B*32-1
        int g = i >> 5, q = i & 31;
        f32x4 z = {0.f, 0.f, 0.f, 0.f};
        out_x4[(size_t)g * 64 + 32 + q] = z;
        if (i < B_GRAPHS / 4) Sbuf4[i] = z;
    }
}

// ---------- K2: window kernel (standalone; W1 frags in regs; boundary atomics) ----------
__global__ __launch_bounds__(256, 4) void window_kernel(
    const float* __restrict__ z_atom,
    const float* __restrict__ W1,
    const float* __restrict__ W2,
    const float* __restrict__ b2,
    const int*   __restrict__ batch,
    const float* __restrict__ hb,
    float*       __restrict__ out_x,
    float*       __restrict__ Sbuf)
{
    __shared__ unsigned short s_zb[WPB][32][PADK];

    const int t    = threadIdx.x;
    const int lane = t & 63;
    const int w    = t >> 6;
    const int l15  = lane & 15;
    const int kc   = lane >> 4;        // 0..3

    // W1^T fragments in registers
    short8 wa[2][4];
    #pragma unroll
    for (int jh = 0; jh < 2; ++jh)
        #pragma unroll
        for (int kb = 0; kb < 4; ++kb)
            #pragma unroll
            for (int i = 0; i < 8; ++i) {
                int k = kb * 32 + kc * 8 + i;
                wa[jh][kb][i] = (short)f2bf(W1[k * HID + jh * 16 + l15]);
            }

    const float b2v = b2[0];
    float w2v[2][4];
    #pragma unroll
    for (int jh = 0; jh < 2; ++jh)
        #pragma unroll
        for (int r = 0; r < 4; ++r)
            w2v[jh][r] = W2[16 * jh + 4 * kc + r];

    unsigned short (*zb)[PADK] = s_zb[w];

    const int win = blockIdx.x * WPB + w;
    const int c0  = win * 32;
    int bv = 0;
    if (lane < 32) bv = batch[c0 + lane];

    const int leftN  = (c0 > 0) ? batch[c0 - 1] : -2;
    const int rightN = (c0 + 32 < N_NODES) ? batch[c0 + 32] : -2;

    float4 hbf[2][2];
    #pragma unroll
    for (int nh = 0; nh < 2; ++nh) {
        int bn = __shfl(bv, l15 + 16 * nh);
        hbf[nh][0] = *(const float4*)&hb[(size_t)bn * HID + 4 * kc];
        hbf[nh][1] = *(const float4*)&hb[(size_t)bn * HID + 16 + 4 * kc];
    }

    const f32x4* za4 = (const f32x4*)z_atom + (size_t)c0 * (D_EMB / 4);
    #pragma unroll
    for (int half = 0; half < 2; ++half) {
        f32x4 tmp[8];
        #pragma unroll
        for (int it = 0; it < 8; ++it) {
            int idx = (half * 8 + it) * 64 + lane;
            int n = idx >> 5, c = idx & 31;
            tmp[it] = __builtin_nontemporal_load(&za4[n * (D_EMB / 4) + c]);
        }
        #pragma unroll
        for (int it = 0; it < 8; ++it) {
            int idx = (half * 8 + it) * 64 + lane;
            int n = idx >> 5, c = idx & 31;
            f32x4 v = tmp[it];
            unsigned lo = (unsigned)f2bf(v[0]) | ((unsigned)f2bf(v[1]) << 16);
            unsigned hi = (unsigned)f2bf(v[2]) | ((unsigned)f2bf(v[3]) << 16);
            *(uint2*)&zb[n][c * 4] = make_uint2(lo, hi);
        }
    }

    f32x4 acc[2][2] = {{{0.f,0.f,0.f,0.f},{0.f,0.f,0.f,0.f}},
                       {{0.f,0.f,0.f,0.f},{0.f,0.f,0.f,0.f}}};
    #pragma unroll
    for (int kb = 0; kb < 4; ++kb) {
        short8 q0 = *(const short8*)&zb[l15][kb * 32 + kc * 8];
        short8 q1 = *(const short8*)&zb[16 + l15][kb * 32 + kc * 8];
        acc[0][0] = __builtin_amdgcn_mfma_f32_16x16x32_bf16(wa[0][kb], q0, acc[0][0], 0, 0, 0);
        acc[1][0] = __builtin_amdgcn_mfma_f32_16x16x32_bf16(wa[1][kb], q0, acc[1][0], 0, 0, 0);
        acc[0][1] = __builtin_amdgcn_mfma_f32_16x16x32_bf16(wa[0][kb], q1, acc[0][1], 0, 0, 0);
        acc[1][1] = __builtin_amdgcn_mfma_f32_16x16x32_bf16(wa[1][kb], q1, acc[1][1], 0, 0, 0);
    }

    float pt[2];
    #pragma unroll
    for (int nh = 0; nh < 2; ++nh) {
        float part = 0.f;
        #pragma unroll
        for (int r = 0; r < 4; ++r) {
            float h = acc[0][nh][r] + (&hbf[nh][0].x)[r];
            h = h > 0.f ? h : 0.01f * h;
            part += h * w2v[0][r];
        }
        #pragma unroll
        for (int r = 0; r < 4; ++r) {
            float h = acc[1][nh][r] + (&hbf[nh][1].x)[r];
            h = h > 0.f ? h : 0.01f * h;
            part += h * w2v[1][r];
        }
        part += __shfl_xor(part, 16);
        part += __shfl_xor(part, 32);
        pt[nh] = __expf(part + b2v);
    }

    // pooling walk; interior graphs -> plain store; boundary graphs -> atomicAdd
    float u0 = 0.f, u1 = 0.f, ss = 0.f;
    int cur = __shfl(bv, 0);
    int a = 0;

    #pragma unroll 4
    for (int n = 0; n < 32; ++n) {
        int bn = __shfl(bv, n);
        if (bn != cur) {
            if (a == 0 && leftN == cur) {
                atomicAdd(&out_x[(size_t)cur * 256 + 128 + lane * 2], u0);
                atomicAdd(&out_x[(size_t)cur * 256 + 129 + lane * 2], u1);
                if (lane == 0) atomicAdd(&Sbuf[cur], ss);
            } else {
                *(float2*)&out_x[(size_t)cur * 256 + 128 + lane * 2] = make_float2(u0, u1);
                if (lane == 0) Sbuf[cur] = ss;
            }
            u0 = u1 = ss = 0.f;
            cur = bn; a = n;
        }
        float pn = (n < 16) ? __shfl(pt[0], n) : __shfl(pt[1], n - 16);
        unsigned zz = *(const unsigned*)&zb[n][lane * 2];
        u0 += pn * bf2f((unsigned short)(zz & 0xffffu));
        u1 += pn * bf2f((unsigned short)(zz >> 16));
        ss += pn;
    }
    {
        bool lb = (a == 0) && (leftN == cur);
        bool rb = (rightN == cur);
        if (lb || rb) {
            atomicAdd(&out_x[(size_t)cur * 256 + 128 + lane * 2], u0);
            atomicAdd(&out_x[(size_t)cur * 256 + 129 + lane * 2], u1);
            if (lane == 0) atomicAdd(&Sbuf[cur], ss);
        } else {
            *(float2*)&out_x[(size_t)cur * 256 + 128 + lane * 2] = make_float2(u0, u1);
            if (lane == 0) Sbuf[cur] = ss;
        }
    }
}

// ---------- K3: tail = finalize (blocks<NB_FIN) + edge copy + edge state ----------
__global__ __launch_bounds__(256) void tail_kernel(
    const float* __restrict__ z_mol,
    const float* __restrict__ Sbuf,
    float*       __restrict__ out_x,
    const f32x4* __restrict__ edge_attr4,
    const f32x4* __restrict__ state_emb4,
    const int*   __restrict__ state,
    const int*   __restrict__ eidx,
    const int*   __restrict__ batch,
    f32x4*       __restrict__ out_e4)
{
    const int bid = blockIdx.x, t = threadIdx.x;
    if (bid < NB_FIN) {
        // finalize: divide accum by S, copy z_mol
        int i = bid * 256 + t;               // B*32 threads
        int g = i >> 5, q = i & 31;
        f32x4 zm = *(const f32x4*)&z_mol[(size_t)g * D_EMB + q * 4];
        *(f32x4*)&out_x[(size_t)g * 256 + q * 4] = zm;
        float inv = 1.f / (Sbuf[g] + 1e-16f);
        f32x4 u = *(f32x4*)&out_x[(size_t)g * 256 + 128 + q * 4];
        u *= inv;
        *(f32x4*)&out_x[(size_t)g * 256 + 128 + q * 4] = u;
    } else if (bid < NB_FIN + NB_COPY) {
        int tid = (bid - NB_FIN) * 256 + t;  // e*8 + q, q<8
        int e = tid >> 3, q = tid & 7;
        f32x4 v = __builtin_nontemporal_load(&edge_attr4[tid]);
        __builtin_nontemporal_store(v, &out_e4[(size_t)e * 24 + q]);
    } else {
        int tid = (bid - NB_FIN - NB_COPY) * 256 + t;  // e*16 + q, q<16
        int e = tid >> 4, q = tid & 15;
        int n = eidx[e];
        int b = batch[n];
        int s = state[b];
        f32x4 v = state_emb4[s * 16 + q];
        __builtin_nontemporal_store(v, &out_e4[(size_t)e * 24 + 8 + q]);
    }
}

extern "C" void kernel_launch(void* const* d_in, const int* in_sizes, int n_in,
                              void* d_out, int out_size, void* d_ws, size_t ws_size,
                              hipStream_t stream)
{
    const float* edge_attr = (const float*)d_in[0];
    const float* z_mol     = (const float*)d_in[1];
    const float* z_atom    = (const float*)d_in[2];
    const float* state_emb = (const float*)d_in[3];
    const float* W1        = (const float*)d_in[4];
    const float* b1        = (const float*)d_in[5];
    const float* W2        = (const float*)d_in[6];
    const float* b2        = (const float*)d_in[7];
    const int*   state     = (const int*)d_in[8];
    const int*   eidx      = (const int*)d_in[9];
    const int*   batch     = (const int*)d_in[10];

    float* out_x = (float*)d_out;
    float* out_e = out_x + (size_t)B_GRAPHS * 256;

    float* hbuf = (float*)d_ws;                                        // B*32 f32
    float* Sbuf = (float*)((char*)d_ws + (size_t)B_GRAPHS * HID * 4);  // B f32

    prep_kernel<<<4096, 256, 0, stream>>>(
        state_emb, W1, b1, state, hbuf, (f32x4*)out_x, (f32x4*)Sbuf);

    window_kernel<<<WIN_BLOCKS, 256, 0, stream>>>(
        z_atom, W1, W2, b2, batch, hbuf, out_x, Sbuf);

    tail_kernel<<<NB_FIN + NB_COPY + NB_STATE, 256, 0, stream>>>(
        z_mol, Sbuf, out_x,
        (const f32x4*)edge_attr, (const f32x4*)state_emb,
        state, eidx, batch, (f32x4*)out_e);
}